// Round 8
// baseline (99.627 us; speedup 1.0000x reference)
//
#include <hip/hip_runtime.h>
#include <hip/hip_bf16.h>

// ---------------- problem constants ----------------
#define NIMG 16
#define CIN 128
#define COUT 256
#define HH 64
#define WW 64
#define KHE 7
#define KW_ 3
#define HP (HH + 6)   // 70
#define WP (WW + 2)   // 66
#define KDIM (CIN * KHE * KW_)  // 2688
#define NKT 42                  // K-tiles of 64

typedef __attribute__((ext_vector_type(8))) short short8;
typedef __attribute__((ext_vector_type(4))) float f32x4;

#define AS1(p) ((const __attribute__((address_space(1))) void*)(p))
#define AS3(p) ((__attribute__((address_space(3))) void*)(p))

// ---------------- kernel 1: pad + NCHW->NHWC transpose + f32->bf16 ----------------
__global__ void __launch_bounds__(256) pad_convert(const float* __restrict__ x,
                                                   ushort* __restrict__ xp) {
  const int bid = blockIdx.x;          // 16*70
  const int n = bid / HP, hp = bid % HP;
  const int h = hp - 3;
  ushort* dst = xp + (size_t)(n * HP + hp) * (WP * CIN);
  const int tid = threadIdx.x;

  if (h < 0 || h >= HH) {
    uint4* p = (uint4*)dst;
    uint4 z; z.x = z.y = z.z = z.w = 0u;
    for (int idx = tid; idx < (WP * CIN * 2) / 16; idx += 256) p[idx] = z;
    return;
  }

  __shared__ ushort t[CIN][WW + 1];
  for (int it = 0; it < (CIN * WW) / 256; ++it) {
    int flat = it * 256 + tid;
    int i = flat >> 6, w = flat & 63;
    float v = x[(((size_t)n * CIN + i) * HH + h) * WW + w];
    __hip_bfloat16 b = __float2bfloat16(v);
    t[i][w] = *(ushort*)&b;
  }
  __syncthreads();
  for (int it = 0; it < (WP * CIN) / 256; ++it) {
    int flat = it * 256 + tid;
    int wp = flat >> 7, i = flat & 127;
    int w = wp - 1;
    ushort v = (w < 0 || w >= WW) ? (ushort)0 : t[i][w];
    dst[flat] = v;
  }
}

// ---------------- kernel 2: build dense bf16 kernel in MFMA-fragment order ----------------
// kb2[kslice][o][32] where kslice = (kh_eff*3+kw)*4 + (i>>5), within-slice = i&31.
__global__ void __launch_bounds__(256) build_kb(const float* __restrict__ weight,
                                                const float* __restrict__ P,
                                                ushort* __restrict__ kb2) {
  int idx = blockIdx.x * 256 + threadIdx.x;
  if (idx >= COUT * KW_ * CIN) return;
  int i = idx & 127;
  int kw = (idx >> 7) % 3;
  int o = idx / (KW_ * CIN);
  int base = (o * CIN + i) * 9 + kw;

  float a[KHE] = {0.f, 0.f, 0.f, 0.f, 0.f, 0.f, 0.f};
#pragma unroll
  for (int kh = 0; kh < 3; ++kh) {
    float wv = weight[base + kh * 3];
    float p = P[base + kh * 3];
    p = fminf(2.f, fmaxf(-2.f, p));
    float pos = (float)(kh + 2) + p;
    float fl = floorf(pos);
    float fr = pos - fl;
    int r0 = (int)fl;
    float c0 = wv * (1.f - fr);
    float c1 = wv * fr;
#pragma unroll
    for (int r = 0; r < KHE; ++r) {
      a[r] += ((r0 == r) ? c0 : 0.f) + ((r0 + 1 == r) ? c1 : 0.f);
    }
  }
#pragma unroll
  for (int r = 0; r < KHE; ++r) {
    __hip_bfloat16 b = __float2bfloat16(a[r]);
    int kslice = (r * 3 + kw) * 4 + (i >> 5);
    kb2[(size_t)kslice * 8192 + o * 32 + (i & 31)] = *(ushort*)&b;
  }
}

// ---------------- kernel 3: implicit-GEMM conv; A via 4-buf LDS, B via L2->regs ----------------
// M = 65536, N = 256 (one tile), K = 2688 = 42 x 64
// 8 waves (2M x 4N), per-wave output 128x64.
// m201-style phase pairs: 4 phases/tile, each {4 ds_read + 1 stage -> barrier ->
// lgkmcnt(0) -> setprio(1) 16 MFMA setprio(0) -> barrier}; B prefetch split into
// phases 3/4; vmcnt(12) once per tile at top.
__global__ void __launch_bounds__(512, 2) dcls_gemm(const ushort* __restrict__ xp,
                                                    const ushort* __restrict__ kb2,
                                                    const float* __restrict__ bias,
                                                    float* __restrict__ out) {
  __shared__ __align__(16) ushort As[4][256 * 64];   // 128 KiB

  const int tid = threadIdx.x;
  const int lane = tid & 63;
  const int wv = tid >> 6;       // 0..7
  const int wr = wv >> 2;        // 0..1 along M
  const int wc = wv & 3;         // 0..3 along N
  const int g = lane >> 4;
  const int lm = lane & 15;
  const int m0 = blockIdx.x << 8;

  // A staging: 512 threads x 16B, source pre-swizzled (rule #21)
  const int srow = tid >> 3;
  const int swz = ((tid & 7) ^ (srow & 7)) * 8;

  const ushort* pA[4];
#pragma unroll
  for (int j = 0; j < 4; ++j) {
    int r = j * 64 + srow;
    int m = m0 + r;
    int ni = m >> 12, hh = (m >> 6) & 63, ww = m & 63;
    pA[j] = xp + (size_t)((ni * HP + hh) * WP + ww) * CIN + swz;
  }

  // B fragment base: lane part of ((kslice*256 + o)*32 + g*8)
  const ushort* kbB = kb2 + (size_t)wc * 2048 + lm * 32 + g * 8;

  // one global_load_lds (1/4 of a tile's A-stage)
#define STAGEA1(buf, kt, j_) do { \
    int kh_ = (kt) / 6; int rem_ = (kt) - kh_ * 6; \
    int kw2_ = rem_ >> 1; int ic_ = rem_ & 1; \
    int offA_ = (kh_ * WP + kw2_) * CIN + ic_ * 64; \
    __builtin_amdgcn_global_load_lds(AS1(pA[j_] + offA_), AS3(&As[buf][((j_) * 64 + wv * 8) * 64]), 16, 0, 0); \
  } while (0)

  // half a tile's B prefetch (one kk slice, 4 loads)
#define LOADB_K(dst, kt, kk_) do { \
    _Pragma("unroll") \
    for (int n_ = 0; n_ < 4; ++n_) \
      dst[n_][kk_] = *(const short8*)(kbB + (size_t)((kt) * 2 + (kk_)) * 8192 + n_ * 512); \
  } while (0)

#define LOADB(dst, kt) do { LOADB_K(dst, kt, 0); LOADB_K(dst, kt, 1); } while (0)

  f32x4 acc[8][4] = {};
  const int swzR = (lm & 7) << 4;

  short8 bf0[4][2], bf1[4][2];
  short8 af[4];

  // 4 ds_read_b128 of one (half,kk) fragment group
#define READ_AF(Ab, half, kk) do { \
    _Pragma("unroll") \
    for (int m4_ = 0; m4_ < 4; ++m4_) { \
      int rowA_ = wr * 128 + (half) * 64 + m4_ * 16 + lm; \
      af[m4_] = *(const short8*)((Ab) + rowA_ * 128 + (((kk) * 64 + g * 16) ^ swzR)); \
    } \
  } while (0)

  // 16 MFMA consuming one fragment group
#define MFMA_G(bfc, half, kk) do { \
    __builtin_amdgcn_s_setprio(1); \
    _Pragma("unroll") \
    for (int m4_ = 0; m4_ < 4; ++m4_) \
      _Pragma("unroll") \
      for (int n_ = 0; n_ < 4; ++n_) \
        acc[(half) * 4 + m4_][n_] = __builtin_amdgcn_mfma_f32_16x16x32_bf16( \
            af[m4_], bfc[n_][kk], acc[(half) * 4 + m4_][n_], 0, 0, 0); \
    __builtin_amdgcn_s_setprio(0); \
  } while (0)

  // barrier then wait own ds_reads (rule #18 fences)
#define BARLG do { \
    __builtin_amdgcn_sched_barrier(0); \
    __builtin_amdgcn_s_barrier(); \
    asm volatile("s_waitcnt lgkmcnt(0)" ::: "memory"); \
    __builtin_amdgcn_sched_barrier(0); \
  } while (0)

#define BAR do { \
    __builtin_amdgcn_sched_barrier(0); \
    __builtin_amdgcn_s_barrier(); \
    __builtin_amdgcn_sched_barrier(0); \
  } while (0)

  // one K-tile: data-ready gate at top, then 4 phase-pairs
#define SUBITER(kt, bfc) do { \
    __builtin_amdgcn_sched_barrier(0); \
    asm volatile("s_waitcnt vmcnt(12)" ::: "memory"); \
    __builtin_amdgcn_s_barrier(); \
    __builtin_amdgcn_sched_barrier(0); \
    int ktn_ = ((kt) + 2 < NKT) ? (kt) + 2 : 0; \
    int buf_ = ((kt) + 2) & 3; \
    const char* Ab = (const char*)&As[(kt) & 3][0]; \
    /* P1 */ READ_AF(Ab, 0, 0); STAGEA1(buf_, ktn_, 0); \
    BARLG; MFMA_G(bfc, 0, 0); BAR; \
    /* P2 */ READ_AF(Ab, 0, 1); STAGEA1(buf_, ktn_, 1); \
    BARLG; MFMA_G(bfc, 0, 1); BAR; \
    /* P3 */ READ_AF(Ab, 1, 0); STAGEA1(buf_, ktn_, 2); \
    BARLG; MFMA_G(bfc, 1, 0); LOADB_K(bfc, ktn_, 0); BAR; \
    /* P4 */ READ_AF(Ab, 1, 1); STAGEA1(buf_, ktn_, 3); \
    BARLG; MFMA_G(bfc, 1, 1); LOADB_K(bfc, ktn_, 1); \
  } while (0)

  // prologue: A0,B0,A1,B1 -> 24 outstanding
  STAGEA1(0, 0, 0); STAGEA1(0, 0, 1); STAGEA1(0, 0, 2); STAGEA1(0, 0, 3);
  LOADB(bf0, 0);
  STAGEA1(1, 1, 0); STAGEA1(1, 1, 1); STAGEA1(1, 1, 2); STAGEA1(1, 1, 3);
  LOADB(bf1, 1);

  for (int kt = 0; kt < NKT; kt += 2) {
    SUBITER(kt, bf0);
    SUBITER(kt + 1, bf1);
  }
#undef SUBITER
#undef BAR
#undef BARLG
#undef MFMA_G
#undef READ_AF
#undef LOADB
#undef LOADB_K
#undef STAGEA1

  // keep tail prefetches alive (vmcnt-count integrity under unroll+DCE)
#pragma unroll
  for (int n_ = 0; n_ < 4; ++n_)
#pragma unroll
    for (int kk_ = 0; kk_ < 2; ++kk_) {
      asm volatile("" :: "v"((int)bf0[n_][kk_][0]));
      asm volatile("" :: "v"((int)bf1[n_][kk_][0]));
    }

  // epilogue: C/D layout col(o)=lane&15, row(m)=(lane>>4)*4+reg; fuse bias
#pragma unroll
  for (int fn = 0; fn < 4; ++fn) {
    int o = wc * 64 + fn * 16 + lm;
    float bv = bias[o];
#pragma unroll
    for (int fm = 0; fm < 8; ++fm) {
      int m = m0 + wr * 128 + fm * 16 + g * 4;
      int ni = m >> 12, hh = (m >> 6) & 63, ww = m & 63;
      f32x4 v = acc[fm][fn];
      v[0] += bv; v[1] += bv; v[2] += bv; v[3] += bv;
      *(f32x4*)(out + (size_t)((ni * COUT + o) * HH + hh) * WW + ww) = v;
    }
  }
}

// ---------------- launcher ----------------
extern "C" void kernel_launch(void* const* d_in, const int* in_sizes, int n_in,
                              void* d_out, int out_size, void* d_ws, size_t ws_size,
                              hipStream_t stream) {
  const float* x = (const float*)d_in[0];
  const float* weight = (const float*)d_in[1];
  const float* bias = (const float*)d_in[2];
  const float* P = (const float*)d_in[3];
  float* out = (float*)d_out;

  const size_t xp_elems = (size_t)NIMG * HP * WP * CIN;
  ushort* xp = (ushort*)d_ws;
  ushort* kb2 = (ushort*)((char*)d_ws + xp_elems * 2);

  hipLaunchKernelGGL(pad_convert, dim3(NIMG * HP), dim3(256), 0, stream, x, xp);
  hipLaunchKernelGGL(build_kb, dim3((COUT * KW_ * CIN + 255) / 256), dim3(256), 0, stream,
                     weight, P, kb2);
  hipLaunchKernelGGL(dcls_gemm, dim3(65536 / 256), dim3(512), 0, stream, xp, kb2, bias, out);
}